// Round 25
// baseline (106.867 us; speedup 1.0000x reference)
//
#include <hip/hip_runtime.h>
#include <math.h>

#define B_ 8
#define N_ 2048
#define H_ 256

typedef double d4 __attribute__((ext_vector_type(4)));

// One-shot: W1T[k][o] = W1[o][k] (f32). Consecutive lanes read consecutive
// o -> coalesced (r19 lesson: lane coalescing beats per-lane load width).
__global__ __launch_bounds__(256)
void transpose_w1(const float* __restrict__ W1, float* __restrict__ W1T) {
    W1T[(size_t)blockIdx.x * H_ + threadIdx.x] =
        W1[(size_t)threadIdx.x * H_ + blockIdx.x];
}

// ---- f64 MFMA rate microbench (diagnostic, this round only) ----
// Pure-register: 4 independent acc chains, 128 iters x 4 mfma = 512
// mfma/wave; 512 blocks x 4 waves -> 2.147 GFLOP total.
// Duration ~27us => 78.6 TF (headroom in s_kernel); ~55us => 39.3 TF
// (s_kernel is at the f64-matrix roofline).
__global__ __launch_bounds__(256)
void mfma_f64_bench(const float* __restrict__ seed, double* __restrict__ sink) {
    const int t = threadIdx.x;
    d4 c0 = {0.0, 0.0, 0.0, 0.0}, c1 = c0, c2 = c0, c3 = c0;
    const double a = (double)seed[t & 63] * 1e-3;
    const double b = (double)seed[(t & 63) + 64] * 1e-3;
    #pragma unroll 4
    for (int i = 0; i < 128; ++i) {
        c0 = __builtin_amdgcn_mfma_f64_16x16x4f64(a, b, c0, 0, 0, 0);
        c1 = __builtin_amdgcn_mfma_f64_16x16x4f64(a, b, c1, 0, 0, 0);
        c2 = __builtin_amdgcn_mfma_f64_16x16x4f64(a, b, c2, 0, 0, 0);
        c3 = __builtin_amdgcn_mfma_f64_16x16x4f64(a, b, c3, 0, 0, 0);
    }
    const double r = c0[0] + c1[1] + c2[2] + c3[3];
    if ((t & 63) == 0)
        sink[(size_t)blockIdx.x * 4 + (t >> 6)] = r;
}

// In-kernel probe of the v_mfma_f64_16x16x4_f64 lane mapping (~200 cy).
// Rounds 15-22 consistently matched one of vars 1-4 on this chip.
__device__ __forceinline__ int self_probe_var() {
    const int l = threadIdx.x & 63;
    d4 z = {0.0, 0.0, 0.0, 0.0};
    d4 r1 = __builtin_amdgcn_mfma_f64_16x16x4f64((double)(l + 1), 1.0, z, 0, 0, 0);
    d4 r2 = __builtin_amdgcn_mfma_f64_16x16x4f64(1.0, (double)(l + 1), z, 0, 0, 0);
    d4 r3 = __builtin_amdgcn_mfma_f64_16x16x4f64((double)(l & 15), 1.0, z, 0, 0, 0);
    const double pw0 = __shfl(r1[0], 0, 64);
    const double pw1 = __shfl(r2[0], 0, 64);
    const double pw2 = __shfl(r3[0], 1, 64);
    const double pw3 = __shfl(r3[2], 16, 64);
    const double pw4 = __shfl(r2[2], 16, 64);
    if (pw0 != 100.0 || pw1 != 100.0) return 0;
    if (pw2 == 0.0 && pw3 == 24.0)  return 1;   // row=4g+v, col=a15
    if (pw2 == 0.0 && pw3 == 36.0)  return 3;   // row=g+4v, col=a15
    if (pw2 == 4.0 && pw4 == 124.0) return 2;   // row=a15,  col=4g+v
    if (pw2 == 4.0 && pw4 == 136.0) return 4;   // row=a15,  col=g+4v
    return 0;
}

// s-kernel (r24, verified @72.8 total): MFMA body + merged VALU fallback.
__global__ __launch_bounds__(256)
__attribute__((amdgpu_waves_per_eu(2, 4)))
void s_kernel(const float* __restrict__ hp, const float* __restrict__ W1T,
              const float* __restrict__ b1, const float* __restrict__ w2,
              double* __restrict__ s_out) {
    __shared__ double spart[4][32];
    const int var = self_probe_var();
    const int t = threadIdx.x;
    const int lane = t & 63;
    const int wave = __builtin_amdgcn_readfirstlane(t >> 6);
    const int m0 = blockIdx.x * 32;

    if (var != 0) {
        // ---------------- MFMA body (r17/r24, verified) ----------------
        const int a15 = lane & 15, g = lane >> 4;
        const int oc = wave * 64;
        const float* ap0 = hp + (size_t)(m0 + a15) * H_ + g;
        const float* ap1 = ap0 + 16 * H_;
        const float* bp  = W1T + (size_t)g * H_ + oc + a15;

        d4 acc[2][4];
        #pragma unroll
        for (int mt = 0; mt < 2; ++mt)
            #pragma unroll
            for (int ot = 0; ot < 4; ++ot) acc[mt][ot] = (d4){0.0, 0.0, 0.0, 0.0};

        float ac[4], an[4];        // A: [mt*2 + half]
        float bcv[8], bnv[8];      // B: [half*4 + ot]
        ac[0] = ap0[0]; ac[1] = ap0[4]; ac[2] = ap1[0]; ac[3] = ap1[4];
        #pragma unroll
        for (int ot = 0; ot < 4; ++ot) {
            bcv[ot]     = bp[ot * 16];
            bcv[4 + ot] = bp[4 * H_ + ot * 16];
        }

        for (int kc = 0; kc < H_; kc += 8) {
            const int kn = (kc + 8 < H_) ? (kc + 8) : 0;      // guarded prefetch
            an[0] = ap0[kn]; an[1] = ap0[kn + 4];
            an[2] = ap1[kn]; an[3] = ap1[kn + 4];
            #pragma unroll
            for (int ot = 0; ot < 4; ++ot) {
                bnv[ot]     = bp[(size_t)kn * H_ + ot * 16];
                bnv[4 + ot] = bp[(size_t)(kn + 4) * H_ + ot * 16];
            }
            {   // k half 0
                const double a0 = (double)ac[0], a1 = (double)ac[2];
                #pragma unroll
                for (int ot = 0; ot < 4; ++ot) {
                    const double bv = (double)bcv[ot];
                    acc[0][ot] = __builtin_amdgcn_mfma_f64_16x16x4f64(a0, bv, acc[0][ot], 0, 0, 0);
                    acc[1][ot] = __builtin_amdgcn_mfma_f64_16x16x4f64(a1, bv, acc[1][ot], 0, 0, 0);
                }
            }
            {   // k half 1
                const double a0 = (double)ac[1], a1 = (double)ac[3];
                #pragma unroll
                for (int ot = 0; ot < 4; ++ot) {
                    const double bv = (double)bcv[4 + ot];
                    acc[0][ot] = __builtin_amdgcn_mfma_f64_16x16x4f64(a0, bv, acc[0][ot], 0, 0, 0);
                    acc[1][ot] = __builtin_amdgcn_mfma_f64_16x16x4f64(a1, bv, acc[1][ot], 0, 0, 0);
                }
            }
            #pragma unroll
            for (int q = 0; q < 4; ++q) ac[q] = an[q];
            #pragma unroll
            for (int q = 0; q < 8; ++q) bcv[q] = bnv[q];
        }

        if (var == 1 || var == 3) {
            double psum[2][4];
            #pragma unroll
            for (int mt = 0; mt < 2; ++mt)
                #pragma unroll
                for (int v = 0; v < 4; ++v) psum[mt][v] = 0.0;
            #pragma unroll
            for (int ot = 0; ot < 4; ++ot) {
                const int o = oc + ot * 16 + a15;
                const double bb = (double)b1[o];
                const double ww = (double)w2[o];
                #pragma unroll
                for (int mt = 0; mt < 2; ++mt)
                    #pragma unroll
                    for (int v = 0; v < 4; ++v) {
                        const double u = acc[mt][ot][v] + bb;
                        psum[mt][v] += ww * (u / (1.0 + exp(-u)));
                    }
            }
            #pragma unroll
            for (int mt = 0; mt < 2; ++mt)
                #pragma unroll
                for (int v = 0; v < 4; ++v) {
                    double x = psum[mt][v];
                    x += __shfl_xor(x, 1, 64);
                    x += __shfl_xor(x, 2, 64);
                    x += __shfl_xor(x, 4, 64);
                    x += __shfl_xor(x, 8, 64);
                    psum[mt][v] = x;
                }
            if (a15 == 0) {
                #pragma unroll
                for (int mt = 0; mt < 2; ++mt)
                    #pragma unroll
                    for (int v = 0; v < 4; ++v) {
                        const int row = (var == 1) ? (4 * g + v) : (g + 4 * v);
                        spart[wave][mt * 16 + row] = psum[mt][v];
                    }
            }
        } else {
            double ps[2] = {0.0, 0.0};
            #pragma unroll
            for (int ot = 0; ot < 4; ++ot)
                #pragma unroll
                for (int v = 0; v < 4; ++v) {
                    const int cv = (var == 2) ? (4 * g + v) : (g + 4 * v);
                    const int o = oc + ot * 16 + cv;
                    const double bb = (double)b1[o];
                    const double ww = (double)w2[o];
                    #pragma unroll
                    for (int mt = 0; mt < 2; ++mt) {
                        const double u = acc[mt][ot][v] + bb;
                        ps[mt] += ww * (u / (1.0 + exp(-u)));
                    }
                }
            #pragma unroll
            for (int mt = 0; mt < 2; ++mt) {
                ps[mt] += __shfl_xor(ps[mt], 16, 64);
                ps[mt] += __shfl_xor(ps[mt], 32, 64);
            }
            if (g == 0) {
                spart[wave][a15]      = ps[0];
                spart[wave][16 + a15] = ps[1];
            }
        }
        __syncthreads();
        if (t < 32)
            s_out[m0 + t] = spart[0][t] + spart[1][t] + spart[2][t] + spart[3][t];
        return;
    }

    // -------- VALU fallback (r12 verified body): wave = 8 rows x all o --------
    {
        const int mv0 = m0 + wave * 8;
        const int o0 = lane * 4;
        const float* hr = hp + (size_t)mv0 * H_;
        const float* wp = W1T + o0;

        double acc[4][8];
        #pragma unroll
        for (int j = 0; j < 4; ++j)
            #pragma unroll
            for (int r = 0; r < 8; ++r) acc[j][r] = 0.0;

        float4 wA[4], wB[4];
        float hA[32], hB[32];     // 8 rows x 4 k

        #define VLOADW(dst, kcv)                                              \
            do {                                                              \
                _Pragma("unroll")                                             \
                for (int kk = 0; kk < 4; ++kk)                                \
                    dst[kk] = *reinterpret_cast<const float4*>(               \
                        wp + (size_t)((kcv) + kk) * H_);                      \
            } while (0)

        #define VLOADH(dst, kcv)                                              \
            do {                                                              \
                _Pragma("unroll")                                             \
                for (int r = 0; r < 8; ++r)                                   \
                    _Pragma("unroll")                                         \
                    for (int kk = 0; kk < 4; ++kk)                            \
                        dst[r * 4 + kk] = hr[r * H_ + (kcv) + kk];            \
            } while (0)

        #define VCOMPUTE(wv, hbuf)                                            \
            do {                                                              \
                _Pragma("unroll")                                             \
                for (int kk = 0; kk < 4; ++kk) {                              \
                    const double a0 = (double)wv[kk].x;                       \
                    const double a1 = (double)wv[kk].y;                       \
                    const double a2 = (double)wv[kk].z;                       \
                    const double a3 = (double)wv[kk].w;                       \
                    _Pragma("unroll")                                         \
                    for (int r = 0; r < 8; ++r) {                             \
                        const double hv = (double)hbuf[r * 4 + kk];           \
                        acc[0][r] = fma(a0, hv, acc[0][r]);                   \
                        acc[1][r] = fma(a1, hv, acc[1][r]);                   \
                        acc[2][r] = fma(a2, hv, acc[2][r]);                   \
                        acc[3][r] = fma(a3, hv, acc[3][r]);                   \
                    }                                                         \
                }                                                             \
            } while (0)

        VLOADW(wA, 0);
        VLOADH(hA, 0);
        for (int kc = 0; kc < H_; kc += 8) {
            VLOADW(wB, kc + 4);
            VLOADH(hB, kc + 4);
            VCOMPUTE(wA, hA);
            if (kc + 8 < H_) {
                VLOADW(wA, kc + 8);
                VLOADH(hA, kc + 8);
            }
            VCOMPUTE(wB, hB);
        }
        #undef VLOADW
        #undef VLOADH
        #undef VCOMPUTE

        const float4 b1v = *reinterpret_cast<const float4*>(b1 + o0);
        const float4 w2v = *reinterpret_cast<const float4*>(w2 + o0);
        double psum[8] = {0.0, 0.0, 0.0, 0.0, 0.0, 0.0, 0.0, 0.0};
        #define VEPI(j, bc, wc)                                               \
            do {                                                              \
                const double bb = (double)bc, ww = (double)wc;                \
                _Pragma("unroll")                                             \
                for (int r = 0; r < 8; ++r) {                                 \
                    const double u = acc[j][r] + bb;                          \
                    psum[r] += ww * (u / (1.0 + exp(-u)));                    \
                }                                                             \
            } while (0)
        VEPI(0, b1v.x, w2v.x);
        VEPI(1, b1v.y, w2v.y);
        VEPI(2, b1v.z, w2v.z);
        VEPI(3, b1v.w, w2v.w);
        #undef VEPI

        #pragma unroll
        for (int r = 0; r < 8; ++r) {
            double v = psum[r];
            v += __shfl_xor(v, 1, 64);
            v += __shfl_xor(v, 2, 64);
            v += __shfl_xor(v, 4, 64);
            v += __shfl_xor(v, 8, 64);
            v += __shfl_xor(v, 16, 64);
            v += __shfl_xor(v, 32, 64);
            if (lane == 0) s_out[mv0 + r] = v;
        }
    }
}

// Kernel B: out[b,i,j] = (int32)trunc( (s[b,i] - s[b,j]) + b2 )
__global__ __launch_bounds__(256)
void pair_kernel(const double* __restrict__ s, const float* __restrict__ b2p,
                 int* __restrict__ out) {
    const double b2 = (double)b2p[0];
    const unsigned total4 = (unsigned)(B_) * (unsigned)(N_) * (unsigned)(N_) / 4u;
    const unsigned stride = gridDim.x * blockDim.x;
    for (unsigned idx = blockIdx.x * blockDim.x + threadIdx.x; idx < total4;
         idx += stride) {
        const unsigned base = idx * 4u;                 // element index, %4==0
        const unsigned bi  = base >> 22;                // / (N*N), N*N = 2^22
        const unsigned rem = base & ((1u << 22) - 1u);
        const unsigned i   = rem >> 11;                 // / N
        const unsigned j   = rem & (N_ - 1u);
        const double si = s[bi * N_ + i];
        const double* sp = s + bi * N_ + j;             // 32B aligned (j%4==0)
        const double sj0 = sp[0], sj1 = sp[1], sj2 = sp[2], sj3 = sp[3];
        int4 o;
        o.x = (int)trunc((si - sj0) + b2);
        o.y = (int)trunc((si - sj1) + b2);
        o.z = (int)trunc((si - sj2) + b2);
        o.w = (int)trunc((si - sj3) + b2);
        *reinterpret_cast<int4*>(out + base) = o;
    }
}

extern "C" void kernel_launch(void* const* d_in, const int* in_sizes, int n_in,
                              void* d_out, int out_size, void* d_ws, size_t ws_size,
                              hipStream_t stream) {
    const float* hp = (const float*)d_in[0];
    // d_in[1] = node_mask (unused), d_in[2] = n_nodes (unused)
    const float* W1 = (const float*)d_in[3];
    const float* b1 = (const float*)d_in[4];
    const float* w2 = (const float*)d_in[5];
    const float* b2 = (const float*)d_in[6];

    float*  W1T  = (float*)d_ws;                                  // 256 KB
    double* s    = (double*)((char*)d_ws + 256 * 1024);           // 128 KB
    double* sink = (double*)((char*)d_ws + 384 * 1024);           // 16 KB
    int* out = (int*)d_out;

    transpose_w1<<<H_, H_, 0, stream>>>(W1, W1T);
    s_kernel<<<(B_ * N_) / 32, 256, 0, stream>>>(hp, W1T, b1, w2, s);
    pair_kernel<<<2048, 256, 0, stream>>>(s, b2, out);
    mfma_f64_bench<<<512, 256, 0, stream>>>(W1, sink);   // diagnostic
}

// Round 26
// 75.458 us; speedup vs baseline: 1.4162x; 1.4162x over previous
//
#include <hip/hip_runtime.h>
#include <math.h>

#define B_ 8
#define N_ 2048
#define H_ 256

typedef double d4 __attribute__((ext_vector_type(4)));

// One-shot: W1T[k][o] = W1[o][k] (f32). Consecutive lanes read consecutive
// o -> coalesced (r19 lesson: lane coalescing beats per-lane load width).
__global__ __launch_bounds__(256)
void transpose_w1(const float* __restrict__ W1, float* __restrict__ W1T) {
    W1T[(size_t)blockIdx.x * H_ + threadIdx.x] =
        W1[(size_t)threadIdx.x * H_ + blockIdx.x];
}

// In-kernel probe of the v_mfma_f64_16x16x4_f64 lane mapping (~200 cy).
// Rounds 15-25 consistently matched one of vars 1-4 on this chip.
__device__ __forceinline__ int self_probe_var() {
    const int l = threadIdx.x & 63;
    d4 z = {0.0, 0.0, 0.0, 0.0};
    d4 r1 = __builtin_amdgcn_mfma_f64_16x16x4f64((double)(l + 1), 1.0, z, 0, 0, 0);
    d4 r2 = __builtin_amdgcn_mfma_f64_16x16x4f64(1.0, (double)(l + 1), z, 0, 0, 0);
    d4 r3 = __builtin_amdgcn_mfma_f64_16x16x4f64((double)(l & 15), 1.0, z, 0, 0, 0);
    const double pw0 = __shfl(r1[0], 0, 64);
    const double pw1 = __shfl(r2[0], 0, 64);
    const double pw2 = __shfl(r3[0], 1, 64);
    const double pw3 = __shfl(r3[2], 16, 64);
    const double pw4 = __shfl(r2[2], 16, 64);
    if (pw0 != 100.0 || pw1 != 100.0) return 0;
    if (pw2 == 0.0 && pw3 == 24.0)  return 1;   // row=4g+v, col=a15
    if (pw2 == 0.0 && pw3 == 36.0)  return 3;   // row=g+4v, col=a15
    if (pw2 == 4.0 && pw4 == 124.0) return 2;   // row=a15,  col=4g+v
    if (pw2 == 4.0 && pw4 == 136.0) return 4;   // row=a15,  col=g+4v
    return 0;
}

// s-kernel, round 26: r24 geometry (32 rows/block, grid 512, wave = 2
// m-tiles x 4 o-tiles, 16 mfma per 8-k chunk) with the inner loop
// restructured as PING-PONG (unroll 2, no buffer copies). r24's rolling
// copies (ac=an; bcv=bnv) forced vmcnt(0) on the same iteration's prefetch
// (in-flight window ~300 cy of issue span only) — r25's ubench proved the
// pipe runs ~78 TF when fed, so the ~50% idle was this stall. Ping-pong
// gives each chunk a full compute-phase of latency cover, zero v_movs.
__global__ __launch_bounds__(256)
__attribute__((amdgpu_waves_per_eu(2, 4)))
void s_kernel(const float* __restrict__ hp, const float* __restrict__ W1T,
              const float* __restrict__ b1, const float* __restrict__ w2,
              double* __restrict__ s_out) {
    __shared__ double spart[4][32];
    const int var = self_probe_var();
    const int t = threadIdx.x;
    const int lane = t & 63;
    const int wave = __builtin_amdgcn_readfirstlane(t >> 6);
    const int m0 = blockIdx.x * 32;

    if (var != 0) {
        // ---------------- MFMA body ----------------
        const int a15 = lane & 15, g = lane >> 4;
        const int oc = wave * 64;
        const float* ap0 = hp + (size_t)(m0 + a15) * H_ + g;
        const float* ap1 = ap0 + 16 * H_;
        const float* bp  = W1T + (size_t)g * H_ + oc + a15;

        d4 acc[2][4];
        #pragma unroll
        for (int mt = 0; mt < 2; ++mt)
            #pragma unroll
            for (int ot = 0; ot < 4; ++ot) acc[mt][ot] = (d4){0.0, 0.0, 0.0, 0.0};

        float aA[4], aB[4];     // A chunk: [mt*2 + half]
        float bA[8], bB[8];     // B chunk: [half*4 + ot]

        #define MLOADA(dst, kcv)                                              \
            do {                                                              \
                dst[0] = ap0[(kcv)];     dst[1] = ap0[(kcv) + 4];             \
                dst[2] = ap1[(kcv)];     dst[3] = ap1[(kcv) + 4];             \
            } while (0)

        #define MLOADB(dst, kcv)                                              \
            do {                                                              \
                _Pragma("unroll")                                             \
                for (int ot = 0; ot < 4; ++ot) {                              \
                    dst[ot]     = bp[(size_t)(kcv) * H_ + ot * 16];           \
                    dst[4 + ot] = bp[(size_t)((kcv) + 4) * H_ + ot * 16];     \
                }                                                             \
            } while (0)

        #define MCOMPUTE(av, bv)                                              \
            do {                                                              \
                {   /* k half 0 */                                            \
                    const double x0 = (double)av[0], x1 = (double)av[2];      \
                    _Pragma("unroll")                                         \
                    for (int ot = 0; ot < 4; ++ot) {                          \
                        const double bb = (double)bv[ot];                     \
                        acc[0][ot] = __builtin_amdgcn_mfma_f64_16x16x4f64(    \
                            x0, bb, acc[0][ot], 0, 0, 0);                     \
                        acc[1][ot] = __builtin_amdgcn_mfma_f64_16x16x4f64(    \
                            x1, bb, acc[1][ot], 0, 0, 0);                     \
                    }                                                         \
                }                                                             \
                {   /* k half 1 */                                            \
                    const double x0 = (double)av[1], x1 = (double)av[3];      \
                    _Pragma("unroll")                                         \
                    for (int ot = 0; ot < 4; ++ot) {                          \
                        const double bb = (double)bv[4 + ot];                 \
                        acc[0][ot] = __builtin_amdgcn_mfma_f64_16x16x4f64(    \
                            x0, bb, acc[0][ot], 0, 0, 0);                     \
                        acc[1][ot] = __builtin_amdgcn_mfma_f64_16x16x4f64(    \
                            x1, bb, acc[1][ot], 0, 0, 0);                     \
                    }                                                         \
                }                                                             \
            } while (0)

        MLOADA(aA, 0);
        MLOADB(bA, 0);
        for (int kc = 0; kc < H_; kc += 16) {
            const int k1 = kc + 8;                            // always < H_
            MLOADA(aB, k1);
            MLOADB(bB, k1);
            MCOMPUTE(aA, bA);                                 // chunk kc
            const int k2 = (kc + 16 < H_) ? (kc + 16) : 0;    // guarded
            MLOADA(aA, k2);
            MLOADB(bA, k2);
            MCOMPUTE(aB, bB);                                 // chunk kc+8
        }
        #undef MLOADA
        #undef MLOADB
        #undef MCOMPUTE

        if (var == 1 || var == 3) {
            double psum[2][4];
            #pragma unroll
            for (int mt = 0; mt < 2; ++mt)
                #pragma unroll
                for (int v = 0; v < 4; ++v) psum[mt][v] = 0.0;
            #pragma unroll
            for (int ot = 0; ot < 4; ++ot) {
                const int o = oc + ot * 16 + a15;
                const double bb = (double)b1[o];
                const double ww = (double)w2[o];
                #pragma unroll
                for (int mt = 0; mt < 2; ++mt)
                    #pragma unroll
                    for (int v = 0; v < 4; ++v) {
                        const double u = acc[mt][ot][v] + bb;
                        psum[mt][v] += ww * (u / (1.0 + exp(-u)));
                    }
            }
            #pragma unroll
            for (int mt = 0; mt < 2; ++mt)
                #pragma unroll
                for (int v = 0; v < 4; ++v) {
                    double x = psum[mt][v];
                    x += __shfl_xor(x, 1, 64);
                    x += __shfl_xor(x, 2, 64);
                    x += __shfl_xor(x, 4, 64);
                    x += __shfl_xor(x, 8, 64);
                    psum[mt][v] = x;
                }
            if (a15 == 0) {
                #pragma unroll
                for (int mt = 0; mt < 2; ++mt)
                    #pragma unroll
                    for (int v = 0; v < 4; ++v) {
                        const int row = (var == 1) ? (4 * g + v) : (g + 4 * v);
                        spart[wave][mt * 16 + row] = psum[mt][v];
                    }
            }
        } else {
            double ps[2] = {0.0, 0.0};
            #pragma unroll
            for (int ot = 0; ot < 4; ++ot)
                #pragma unroll
                for (int v = 0; v < 4; ++v) {
                    const int cv = (var == 2) ? (4 * g + v) : (g + 4 * v);
                    const int o = oc + ot * 16 + cv;
                    const double bb = (double)b1[o];
                    const double ww = (double)w2[o];
                    #pragma unroll
                    for (int mt = 0; mt < 2; ++mt) {
                        const double u = acc[mt][ot][v] + bb;
                        ps[mt] += ww * (u / (1.0 + exp(-u)));
                    }
                }
            #pragma unroll
            for (int mt = 0; mt < 2; ++mt) {
                ps[mt] += __shfl_xor(ps[mt], 16, 64);
                ps[mt] += __shfl_xor(ps[mt], 32, 64);
            }
            if (g == 0) {
                spart[wave][a15]      = ps[0];
                spart[wave][16 + a15] = ps[1];
            }
        }
        __syncthreads();
        if (t < 32)
            s_out[m0 + t] = spart[0][t] + spart[1][t] + spart[2][t] + spart[3][t];
        return;
    }

    // -------- VALU fallback (r12 verified body): wave = 8 rows x all o --------
    {
        const int mv0 = m0 + wave * 8;
        const int o0 = lane * 4;
        const float* hr = hp + (size_t)mv0 * H_;
        const float* wp = W1T + o0;

        double acc[4][8];
        #pragma unroll
        for (int j = 0; j < 4; ++j)
            #pragma unroll
            for (int r = 0; r < 8; ++r) acc[j][r] = 0.0;

        float4 wA[4], wB[4];
        float hA[32], hB[32];     // 8 rows x 4 k

        #define VLOADW(dst, kcv)                                              \
            do {                                                              \
                _Pragma("unroll")                                             \
                for (int kk = 0; kk < 4; ++kk)                                \
                    dst[kk] = *reinterpret_cast<const float4*>(               \
                        wp + (size_t)((kcv) + kk) * H_);                      \
            } while (0)

        #define VLOADH(dst, kcv)                                              \
            do {                                                              \
                _Pragma("unroll")                                             \
                for (int r = 0; r < 8; ++r)                                   \
                    _Pragma("unroll")                                         \
                    for (int kk = 0; kk < 4; ++kk)                            \
                        dst[r * 4 + kk] = hr[r * H_ + (kcv) + kk];            \
            } while (0)

        #define VCOMPUTE(wv, hbuf)                                            \
            do {                                                              \
                _Pragma("unroll")                                             \
                for (int kk = 0; kk < 4; ++kk) {                              \
                    const double a0 = (double)wv[kk].x;                       \
                    const double a1 = (double)wv[kk].y;                       \
                    const double a2 = (double)wv[kk].z;                       \
                    const double a3 = (double)wv[kk].w;                       \
                    _Pragma("unroll")                                         \
                    for (int r = 0; r < 8; ++r) {                             \
                        const double hv = (double)hbuf[r * 4 + kk];           \
                        acc[0][r] = fma(a0, hv, acc[0][r]);                   \
                        acc[1][r] = fma(a1, hv, acc[1][r]);                   \
                        acc[2][r] = fma(a2, hv, acc[2][r]);                   \
                        acc[3][r] = fma(a3, hv, acc[3][r]);                   \
                    }                                                         \
                }                                                             \
            } while (0)

        VLOADW(wA, 0);
        VLOADH(hA, 0);
        for (int kc = 0; kc < H_; kc += 8) {
            VLOADW(wB, kc + 4);
            VLOADH(hB, kc + 4);
            VCOMPUTE(wA, hA);
            if (kc + 8 < H_) {
                VLOADW(wA, kc + 8);
                VLOADH(hA, kc + 8);
            }
            VCOMPUTE(wB, hB);
        }
        #undef VLOADW
        #undef VLOADH
        #undef VCOMPUTE

        const float4 b1v = *reinterpret_cast<const float4*>(b1 + o0);
        const float4 w2v = *reinterpret_cast<const float4*>(w2 + o0);
        double psum[8] = {0.0, 0.0, 0.0, 0.0, 0.0, 0.0, 0.0, 0.0};
        #define VEPI(j, bc, wc)                                               \
            do {                                                              \
                const double bb = (double)bc, ww = (double)wc;                \
                _Pragma("unroll")                                             \
                for (int r = 0; r < 8; ++r) {                                 \
                    const double u = acc[j][r] + bb;                          \
                    psum[r] += ww * (u / (1.0 + exp(-u)));                    \
                }                                                             \
            } while (0)
        VEPI(0, b1v.x, w2v.x);
        VEPI(1, b1v.y, w2v.y);
        VEPI(2, b1v.z, w2v.z);
        VEPI(3, b1v.w, w2v.w);
        #undef VEPI

        #pragma unroll
        for (int r = 0; r < 8; ++r) {
            double v = psum[r];
            v += __shfl_xor(v, 1, 64);
            v += __shfl_xor(v, 2, 64);
            v += __shfl_xor(v, 4, 64);
            v += __shfl_xor(v, 8, 64);
            v += __shfl_xor(v, 16, 64);
            v += __shfl_xor(v, 32, 64);
            if (lane == 0) s_out[mv0 + r] = v;
        }
    }
}

// Kernel B: out[b,i,j] = (int32)trunc( (s[b,i] - s[b,j]) + b2 )
__global__ __launch_bounds__(256)
void pair_kernel(const double* __restrict__ s, const float* __restrict__ b2p,
                 int* __restrict__ out) {
    const double b2 = (double)b2p[0];
    const unsigned total4 = (unsigned)(B_) * (unsigned)(N_) * (unsigned)(N_) / 4u;
    const unsigned stride = gridDim.x * blockDim.x;
    for (unsigned idx = blockIdx.x * blockDim.x + threadIdx.x; idx < total4;
         idx += stride) {
        const unsigned base = idx * 4u;                 // element index, %4==0
        const unsigned bi  = base >> 22;                // / (N*N), N*N = 2^22
        const unsigned rem = base & ((1u << 22) - 1u);
        const unsigned i   = rem >> 11;                 // / N
        const unsigned j   = rem & (N_ - 1u);
        const double si = s[bi * N_ + i];
        const double* sp = s + bi * N_ + j;             // 32B aligned (j%4==0)
        const double sj0 = sp[0], sj1 = sp[1], sj2 = sp[2], sj3 = sp[3];
        int4 o;
        o.x = (int)trunc((si - sj0) + b2);
        o.y = (int)trunc((si - sj1) + b2);
        o.z = (int)trunc((si - sj2) + b2);
        o.w = (int)trunc((si - sj3) + b2);
        *reinterpret_cast<int4*>(out + base) = o;
    }
}

extern "C" void kernel_launch(void* const* d_in, const int* in_sizes, int n_in,
                              void* d_out, int out_size, void* d_ws, size_t ws_size,
                              hipStream_t stream) {
    const float* hp = (const float*)d_in[0];
    // d_in[1] = node_mask (unused), d_in[2] = n_nodes (unused)
    const float* W1 = (const float*)d_in[3];
    const float* b1 = (const float*)d_in[4];
    const float* w2 = (const float*)d_in[5];
    const float* b2 = (const float*)d_in[6];

    float*  W1T = (float*)d_ws;                                   // 256 KB
    double* s   = (double*)((char*)d_ws + 256 * 1024);            // 128 KB
    int* out = (int*)d_out;

    transpose_w1<<<H_, H_, 0, stream>>>(W1, W1T);
    s_kernel<<<(B_ * N_) / 32, 256, 0, stream>>>(hp, W1T, b1, w2, s);
    pair_kernel<<<2048, 256, 0, stream>>>(s, b2, out);
}

// Round 27
// 73.690 us; speedup vs baseline: 1.4502x; 1.0240x over previous
//
#include <hip/hip_runtime.h>
#include <math.h>

#define B_ 8
#define N_ 2048
#define H_ 256

typedef double d4 __attribute__((ext_vector_type(4)));

// One-shot: W1T[k][o] = W1[o][k] (f32). Consecutive lanes read consecutive
// o -> coalesced (r19 lesson: lane coalescing beats per-lane load width).
__global__ __launch_bounds__(256)
void transpose_w1(const float* __restrict__ W1, float* __restrict__ W1T) {
    W1T[(size_t)blockIdx.x * H_ + threadIdx.x] =
        W1[(size_t)threadIdx.x * H_ + blockIdx.x];
}

// In-kernel probe of the v_mfma_f64_16x16x4_f64 lane mapping (~200 cy).
// Rounds 15-26 consistently matched one of vars 1-4 on this chip.
__device__ __forceinline__ int self_probe_var() {
    const int l = threadIdx.x & 63;
    d4 z = {0.0, 0.0, 0.0, 0.0};
    d4 r1 = __builtin_amdgcn_mfma_f64_16x16x4f64((double)(l + 1), 1.0, z, 0, 0, 0);
    d4 r2 = __builtin_amdgcn_mfma_f64_16x16x4f64(1.0, (double)(l + 1), z, 0, 0, 0);
    d4 r3 = __builtin_amdgcn_mfma_f64_16x16x4f64((double)(l & 15), 1.0, z, 0, 0, 0);
    const double pw0 = __shfl(r1[0], 0, 64);
    const double pw1 = __shfl(r2[0], 0, 64);
    const double pw2 = __shfl(r3[0], 1, 64);
    const double pw3 = __shfl(r3[2], 16, 64);
    const double pw4 = __shfl(r2[2], 16, 64);
    if (pw0 != 100.0 || pw1 != 100.0) return 0;
    if (pw2 == 0.0 && pw3 == 24.0)  return 1;   // row=4g+v, col=a15
    if (pw2 == 0.0 && pw3 == 36.0)  return 3;   // row=g+4v, col=a15
    if (pw2 == 4.0 && pw4 == 124.0) return 2;   // row=a15,  col=4g+v
    if (pw2 == 4.0 && pw4 == 136.0) return 4;   // row=a15,  col=g+4v
    return 0;
}

#define HSTRIDE 40   // hs_t row stride (floats): (g*40)%32=8g -> A-read is
                     // exactly 2 lanes/bank = conflict-free (m136)

// s-kernel, round 27: r24's verified geometry (32 rows/block, grid 512,
// wave = 2 m-tiles x 4 o-tiles, 16 mfma / 8-k chunk, B ping-pong from
// L2-resident W1T) + A staged ONCE in LDS, transposed + stride-40 padded:
//   hs_t[k][row] ; A-read hs_t[kc+4h+g][mt*16+a15] -> 2-way bank = free.
// Removes the in-loop HBM A-loads (~900cy first-touch latency) that the
// r25 ubench (pure-reg = 32us vs body 52us) identified as the feed stall.
// r21's flat result was its 16-way-conflict LDS layout, not staging itself.
__global__ __launch_bounds__(256)
__attribute__((amdgpu_waves_per_eu(2, 4)))
void s_kernel(const float* __restrict__ hp, const float* __restrict__ W1T,
              const float* __restrict__ b1, const float* __restrict__ w2,
              double* __restrict__ s_out) {
    __shared__ float hs_t[H_ * HSTRIDE];        // 40 KB, [k][row]
    __shared__ double spart[4][32];
    const int var = self_probe_var();
    const int t = threadIdx.x;
    const int lane = t & 63;
    const int wave = __builtin_amdgcn_readfirstlane(t >> 6);
    const int m0 = blockIdx.x * 32;

    if (var != 0) {
        // ---------------- MFMA body ----------------
        const int a15 = lane & 15, g = lane >> 4;
        const int oc = wave * 64;

        // Stage h transposed: thread t = k, rows 0..31. Global coalesced;
        // LDS write 16-way conflict but one-time (~0.5us, vs 32 chunks).
        #pragma unroll
        for (int i = 0; i < 32; ++i)
            hs_t[t * HSTRIDE + i] = hp[(size_t)(m0 + i) * H_ + t];
        __syncthreads();

        const float* bp = W1T + (size_t)g * H_ + oc + a15;

        d4 acc[2][4];
        #pragma unroll
        for (int mt = 0; mt < 2; ++mt)
            #pragma unroll
            for (int ot = 0; ot < 4; ++ot) acc[mt][ot] = (d4){0.0, 0.0, 0.0, 0.0};

        float bA[8], bB[8];     // B chunk: [half*4 + ot]

        #define MLOADB(dst, kcv)                                              \
            do {                                                              \
                _Pragma("unroll")                                             \
                for (int ot = 0; ot < 4; ++ot) {                              \
                    dst[ot]     = bp[(size_t)(kcv) * H_ + ot * 16];           \
                    dst[4 + ot] = bp[(size_t)((kcv) + 4) * H_ + ot * 16];     \
                }                                                             \
            } while (0)

        // A from LDS (2-way bank = free; lgkmcnt-covered) + 16 mfma.
        #define MCOMPUTE(kcv, bv)                                             \
            do {                                                              \
                const float a00 = hs_t[((kcv) + g) * HSTRIDE + a15];          \
                const float a01 = hs_t[((kcv) + 4 + g) * HSTRIDE + a15];      \
                const float a10 = hs_t[((kcv) + g) * HSTRIDE + 16 + a15];     \
                const float a11 = hs_t[((kcv) + 4 + g) * HSTRIDE + 16 + a15]; \
                {   /* k half 0 */                                            \
                    const double x0 = (double)a00, x1 = (double)a10;          \
                    _Pragma("unroll")                                         \
                    for (int ot = 0; ot < 4; ++ot) {                          \
                        const double bb = (double)bv[ot];                     \
                        acc[0][ot] = __builtin_amdgcn_mfma_f64_16x16x4f64(    \
                            x0, bb, acc[0][ot], 0, 0, 0);                     \
                        acc[1][ot] = __builtin_amdgcn_mfma_f64_16x16x4f64(    \
                            x1, bb, acc[1][ot], 0, 0, 0);                     \
                    }                                                         \
                }                                                             \
                {   /* k half 1 */                                            \
                    const double x0 = (double)a01, x1 = (double)a11;          \
                    _Pragma("unroll")                                         \
                    for (int ot = 0; ot < 4; ++ot) {                          \
                        const double bb = (double)bv[4 + ot];                 \
                        acc[0][ot] = __builtin_amdgcn_mfma_f64_16x16x4f64(    \
                            x0, bb, acc[0][ot], 0, 0, 0);                     \
                        acc[1][ot] = __builtin_amdgcn_mfma_f64_16x16x4f64(    \
                            x1, bb, acc[1][ot], 0, 0, 0);                     \
                    }                                                         \
                }                                                             \
            } while (0)

        MLOADB(bA, 0);
        for (int kc = 0; kc < H_; kc += 16) {
            MLOADB(bB, kc + 8);                               // prefetch
            MCOMPUTE(kc, bA);                                 // chunk kc
            const int k2 = (kc + 16 < H_) ? (kc + 16) : 0;    // guarded
            MLOADB(bA, k2);
            MCOMPUTE(kc + 8, bB);                             // chunk kc+8
        }
        #undef MLOADB
        #undef MCOMPUTE

        if (var == 1 || var == 3) {
            double psum[2][4];
            #pragma unroll
            for (int mt = 0; mt < 2; ++mt)
                #pragma unroll
                for (int v = 0; v < 4; ++v) psum[mt][v] = 0.0;
            #pragma unroll
            for (int ot = 0; ot < 4; ++ot) {
                const int o = oc + ot * 16 + a15;
                const double bb = (double)b1[o];
                const double ww = (double)w2[o];
                #pragma unroll
                for (int mt = 0; mt < 2; ++mt)
                    #pragma unroll
                    for (int v = 0; v < 4; ++v) {
                        const double u = acc[mt][ot][v] + bb;
                        psum[mt][v] += ww * (u / (1.0 + exp(-u)));
                    }
            }
            #pragma unroll
            for (int mt = 0; mt < 2; ++mt)
                #pragma unroll
                for (int v = 0; v < 4; ++v) {
                    double x = psum[mt][v];
                    x += __shfl_xor(x, 1, 64);
                    x += __shfl_xor(x, 2, 64);
                    x += __shfl_xor(x, 4, 64);
                    x += __shfl_xor(x, 8, 64);
                    psum[mt][v] = x;
                }
            if (a15 == 0) {
                #pragma unroll
                for (int mt = 0; mt < 2; ++mt)
                    #pragma unroll
                    for (int v = 0; v < 4; ++v) {
                        const int row = (var == 1) ? (4 * g + v) : (g + 4 * v);
                        spart[wave][mt * 16 + row] = psum[mt][v];
                    }
            }
        } else {
            double ps[2] = {0.0, 0.0};
            #pragma unroll
            for (int ot = 0; ot < 4; ++ot)
                #pragma unroll
                for (int v = 0; v < 4; ++v) {
                    const int cv = (var == 2) ? (4 * g + v) : (g + 4 * v);
                    const int o = oc + ot * 16 + cv;
                    const double bb = (double)b1[o];
                    const double ww = (double)w2[o];
                    #pragma unroll
                    for (int mt = 0; mt < 2; ++mt) {
                        const double u = acc[mt][ot][v] + bb;
                        ps[mt] += ww * (u / (1.0 + exp(-u)));
                    }
                }
            #pragma unroll
            for (int mt = 0; mt < 2; ++mt) {
                ps[mt] += __shfl_xor(ps[mt], 16, 64);
                ps[mt] += __shfl_xor(ps[mt], 32, 64);
            }
            if (g == 0) {
                spart[wave][a15]      = ps[0];
                spart[wave][16 + a15] = ps[1];
            }
        }
        __syncthreads();
        if (t < 32)
            s_out[m0 + t] = spart[0][t] + spart[1][t] + spart[2][t] + spart[3][t];
        return;
    }

    // -------- VALU fallback (r12 verified body): wave = 8 rows x all o --------
    {
        const int mv0 = m0 + wave * 8;
        const int o0 = lane * 4;
        const float* hr = hp + (size_t)mv0 * H_;
        const float* wp = W1T + o0;

        double acc[4][8];
        #pragma unroll
        for (int j = 0; j < 4; ++j)
            #pragma unroll
            for (int r = 0; r < 8; ++r) acc[j][r] = 0.0;

        float4 wA[4], wB[4];
        float hA[32], hB[32];     // 8 rows x 4 k

        #define VLOADW(dst, kcv)                                              \
            do {                                                              \
                _Pragma("unroll")                                             \
                for (int kk = 0; kk < 4; ++kk)                                \
                    dst[kk] = *reinterpret_cast<const float4*>(               \
                        wp + (size_t)((kcv) + kk) * H_);                      \
            } while (0)

        #define VLOADH(dst, kcv)                                              \
            do {                                                              \
                _Pragma("unroll")                                             \
                for (int r = 0; r < 8; ++r)                                   \
                    _Pragma("unroll")                                         \
                    for (int kk = 0; kk < 4; ++kk)                            \
                        dst[r * 4 + kk] = hr[r * H_ + (kcv) + kk];            \
            } while (0)

        #define VCOMPUTE(wv, hbuf)                                            \
            do {                                                              \
                _Pragma("unroll")                                             \
                for (int kk = 0; kk < 4; ++kk) {                              \
                    const double a0 = (double)wv[kk].x;                       \
                    const double a1 = (double)wv[kk].y;                       \
                    const double a2 = (double)wv[kk].z;                       \
                    const double a3 = (double)wv[kk].w;                       \
                    _Pragma("unroll")                                         \
                    for (int r = 0; r < 8; ++r) {                             \
                        const double hv = (double)hbuf[r * 4 + kk];           \
                        acc[0][r] = fma(a0, hv, acc[0][r]);                   \
                        acc[1][r] = fma(a1, hv, acc[1][r]);                   \
                        acc[2][r] = fma(a2, hv, acc[2][r]);                   \
                        acc[3][r] = fma(a3, hv, acc[3][r]);                   \
                    }                                                         \
                }                                                             \
            } while (0)

        VLOADW(wA, 0);
        VLOADH(hA, 0);
        for (int kc = 0; kc < H_; kc += 8) {
            VLOADW(wB, kc + 4);
            VLOADH(hB, kc + 4);
            VCOMPUTE(wA, hA);
            if (kc + 8 < H_) {
                VLOADW(wA, kc + 8);
                VLOADH(hA, kc + 8);
            }
            VCOMPUTE(wB, hB);
        }
        #undef VLOADW
        #undef VLOADH
        #undef VCOMPUTE

        const float4 b1v = *reinterpret_cast<const float4*>(b1 + o0);
        const float4 w2v = *reinterpret_cast<const float4*>(w2 + o0);
        double psum[8] = {0.0, 0.0, 0.0, 0.0, 0.0, 0.0, 0.0, 0.0};
        #define VEPI(j, bc, wc)                                               \
            do {                                                              \
                const double bb = (double)bc, ww = (double)wc;                \
                _Pragma("unroll")                                             \
                for (int r = 0; r < 8; ++r) {                                 \
                    const double u = acc[j][r] + bb;                          \
                    psum[r] += ww * (u / (1.0 + exp(-u)));                    \
                }                                                             \
            } while (0)
        VEPI(0, b1v.x, w2v.x);
        VEPI(1, b1v.y, w2v.y);
        VEPI(2, b1v.z, w2v.z);
        VEPI(3, b1v.w, w2v.w);
        #undef VEPI

        #pragma unroll
        for (int r = 0; r < 8; ++r) {
            double v = psum[r];
            v += __shfl_xor(v, 1, 64);
            v += __shfl_xor(v, 2, 64);
            v += __shfl_xor(v, 4, 64);
            v += __shfl_xor(v, 8, 64);
            v += __shfl_xor(v, 16, 64);
            v += __shfl_xor(v, 32, 64);
            if (lane == 0) s_out[mv0 + r] = v;
        }
    }
}

// Kernel B: out[b,i,j] = (int32)trunc( (s[b,i] - s[b,j]) + b2 )
__global__ __launch_bounds__(256)
void pair_kernel(const double* __restrict__ s, const float* __restrict__ b2p,
                 int* __restrict__ out) {
    const double b2 = (double)b2p[0];
    const unsigned total4 = (unsigned)(B_) * (unsigned)(N_) * (unsigned)(N_) / 4u;
    const unsigned stride = gridDim.x * blockDim.x;
    for (unsigned idx = blockIdx.x * blockDim.x + threadIdx.x; idx < total4;
         idx += stride) {
        const unsigned base = idx * 4u;                 // element index, %4==0
        const unsigned bi  = base >> 22;                // / (N*N), N*N = 2^22
        const unsigned rem = base & ((1u << 22) - 1u);
        const unsigned i   = rem >> 11;                 // / N
        const unsigned j   = rem & (N_ - 1u);
        const double si = s[bi * N_ + i];
        const double* sp = s + bi * N_ + j;             // 32B aligned (j%4==0)
        const double sj0 = sp[0], sj1 = sp[1], sj2 = sp[2], sj3 = sp[3];
        int4 o;
        o.x = (int)trunc((si - sj0) + b2);
        o.y = (int)trunc((si - sj1) + b2);
        o.z = (int)trunc((si - sj2) + b2);
        o.w = (int)trunc((si - sj3) + b2);
        *reinterpret_cast<int4*>(out + base) = o;
    }
}

extern "C" void kernel_launch(void* const* d_in, const int* in_sizes, int n_in,
                              void* d_out, int out_size, void* d_ws, size_t ws_size,
                              hipStream_t stream) {
    const float* hp = (const float*)d_in[0];
    // d_in[1] = node_mask (unused), d_in[2] = n_nodes (unused)
    const float* W1 = (const float*)d_in[3];
    const float* b1 = (const float*)d_in[4];
    const float* w2 = (const float*)d_in[5];
    const float* b2 = (const float*)d_in[6];

    float*  W1T = (float*)d_ws;                                   // 256 KB
    double* s   = (double*)((char*)d_ws + 256 * 1024);            // 128 KB
    int* out = (int*)d_out;

    transpose_w1<<<H_, H_, 0, stream>>>(W1, W1T);
    s_kernel<<<(B_ * N_) / 32, 256, 0, stream>>>(hp, W1T, b1, w2, s);
    pair_kernel<<<2048, 256, 0, stream>>>(s, b2, out);
}

// Round 28
// 72.356 us; speedup vs baseline: 1.4770x; 1.0184x over previous
//
#include <hip/hip_runtime.h>
#include <math.h>

#define B_ 8
#define N_ 2048
#define H_ 256

typedef double d4 __attribute__((ext_vector_type(4)));

// One-shot: W1T[k][o] = W1[o][k] (f32). Consecutive lanes read consecutive
// o -> coalesced (r19 lesson: lane coalescing beats per-lane load width).
__global__ __launch_bounds__(256)
void transpose_w1(const float* __restrict__ W1, float* __restrict__ W1T) {
    W1T[(size_t)blockIdx.x * H_ + threadIdx.x] =
        W1[(size_t)threadIdx.x * H_ + blockIdx.x];
}

// In-kernel probe of the v_mfma_f64_16x16x4_f64 lane mapping (~200 cy).
// Rounds 15-27 consistently matched one of vars 1-4 on this chip.
__device__ __forceinline__ int self_probe_var() {
    const int l = threadIdx.x & 63;
    d4 z = {0.0, 0.0, 0.0, 0.0};
    d4 r1 = __builtin_amdgcn_mfma_f64_16x16x4f64((double)(l + 1), 1.0, z, 0, 0, 0);
    d4 r2 = __builtin_amdgcn_mfma_f64_16x16x4f64(1.0, (double)(l + 1), z, 0, 0, 0);
    d4 r3 = __builtin_amdgcn_mfma_f64_16x16x4f64((double)(l & 15), 1.0, z, 0, 0, 0);
    const double pw0 = __shfl(r1[0], 0, 64);
    const double pw1 = __shfl(r2[0], 0, 64);
    const double pw2 = __shfl(r3[0], 1, 64);
    const double pw3 = __shfl(r3[2], 16, 64);
    const double pw4 = __shfl(r2[2], 16, 64);
    if (pw0 != 100.0 || pw1 != 100.0) return 0;
    if (pw2 == 0.0 && pw3 == 24.0)  return 1;   // row=4g+v, col=a15
    if (pw2 == 0.0 && pw3 == 36.0)  return 3;   // row=g+4v, col=a15
    if (pw2 == 4.0 && pw4 == 124.0) return 2;   // row=a15,  col=4g+v
    if (pw2 == 4.0 && pw4 == 136.0) return 4;   // row=a15,  col=g+4v
    return 0;
}

// s-kernel: EXACT r24 build (verified best, 72.8 us total). 32 rows/block,
// grid 512, 4 waves; wave = 2 m-tiles x 4 o-tiles (8 indep acc chains);
// per 8-k iter: 16 mfma vs 12 coalesced scalar loads, one-iter prefetch.
// Merged VALU fallback (var==0; never taken on this chip).
__global__ __launch_bounds__(256)
__attribute__((amdgpu_waves_per_eu(2, 4)))
void s_kernel(const float* __restrict__ hp, const float* __restrict__ W1T,
              const float* __restrict__ b1, const float* __restrict__ w2,
              double* __restrict__ s_out) {
    __shared__ double spart[4][32];
    const int var = self_probe_var();
    const int t = threadIdx.x;
    const int lane = t & 63;
    const int wave = __builtin_amdgcn_readfirstlane(t >> 6);
    const int m0 = blockIdx.x * 32;

    if (var != 0) {
        // ---------------- MFMA body (r17/r24, verified) ----------------
        const int a15 = lane & 15, g = lane >> 4;
        const int oc = wave * 64;
        const float* ap0 = hp + (size_t)(m0 + a15) * H_ + g;
        const float* ap1 = ap0 + 16 * H_;
        const float* bp  = W1T + (size_t)g * H_ + oc + a15;

        d4 acc[2][4];
        #pragma unroll
        for (int mt = 0; mt < 2; ++mt)
            #pragma unroll
            for (int ot = 0; ot < 4; ++ot) acc[mt][ot] = (d4){0.0, 0.0, 0.0, 0.0};

        float ac[4], an[4];        // A: [mt*2 + half]
        float bcv[8], bnv[8];      // B: [half*4 + ot]
        ac[0] = ap0[0]; ac[1] = ap0[4]; ac[2] = ap1[0]; ac[3] = ap1[4];
        #pragma unroll
        for (int ot = 0; ot < 4; ++ot) {
            bcv[ot]     = bp[ot * 16];
            bcv[4 + ot] = bp[4 * H_ + ot * 16];
        }

        for (int kc = 0; kc < H_; kc += 8) {
            const int kn = (kc + 8 < H_) ? (kc + 8) : 0;      // guarded prefetch
            an[0] = ap0[kn]; an[1] = ap0[kn + 4];
            an[2] = ap1[kn]; an[3] = ap1[kn + 4];
            #pragma unroll
            for (int ot = 0; ot < 4; ++ot) {
                bnv[ot]     = bp[(size_t)kn * H_ + ot * 16];
                bnv[4 + ot] = bp[(size_t)(kn + 4) * H_ + ot * 16];
            }
            {   // k half 0
                const double a0 = (double)ac[0], a1 = (double)ac[2];
                #pragma unroll
                for (int ot = 0; ot < 4; ++ot) {
                    const double bv = (double)bcv[ot];
                    acc[0][ot] = __builtin_amdgcn_mfma_f64_16x16x4f64(a0, bv, acc[0][ot], 0, 0, 0);
                    acc[1][ot] = __builtin_amdgcn_mfma_f64_16x16x4f64(a1, bv, acc[1][ot], 0, 0, 0);
                }
            }
            {   // k half 1
                const double a0 = (double)ac[1], a1 = (double)ac[3];
                #pragma unroll
                for (int ot = 0; ot < 4; ++ot) {
                    const double bv = (double)bcv[4 + ot];
                    acc[0][ot] = __builtin_amdgcn_mfma_f64_16x16x4f64(a0, bv, acc[0][ot], 0, 0, 0);
                    acc[1][ot] = __builtin_amdgcn_mfma_f64_16x16x4f64(a1, bv, acc[1][ot], 0, 0, 0);
                }
            }
            #pragma unroll
            for (int q = 0; q < 4; ++q) ac[q] = an[q];
            #pragma unroll
            for (int q = 0; q < 8; ++q) bcv[q] = bnv[q];
        }

        if (var == 1 || var == 3) {
            double psum[2][4];
            #pragma unroll
            for (int mt = 0; mt < 2; ++mt)
                #pragma unroll
                for (int v = 0; v < 4; ++v) psum[mt][v] = 0.0;
            #pragma unroll
            for (int ot = 0; ot < 4; ++ot) {
                const int o = oc + ot * 16 + a15;
                const double bb = (double)b1[o];
                const double ww = (double)w2[o];
                #pragma unroll
                for (int mt = 0; mt < 2; ++mt)
                    #pragma unroll
                    for (int v = 0; v < 4; ++v) {
                        const double u = acc[mt][ot][v] + bb;
                        psum[mt][v] += ww * (u / (1.0 + exp(-u)));
                    }
            }
            #pragma unroll
            for (int mt = 0; mt < 2; ++mt)
                #pragma unroll
                for (int v = 0; v < 4; ++v) {
                    double x = psum[mt][v];
                    x += __shfl_xor(x, 1, 64);
                    x += __shfl_xor(x, 2, 64);
                    x += __shfl_xor(x, 4, 64);
                    x += __shfl_xor(x, 8, 64);
                    psum[mt][v] = x;
                }
            if (a15 == 0) {
                #pragma unroll
                for (int mt = 0; mt < 2; ++mt)
                    #pragma unroll
                    for (int v = 0; v < 4; ++v) {
                        const int row = (var == 1) ? (4 * g + v) : (g + 4 * v);
                        spart[wave][mt * 16 + row] = psum[mt][v];
                    }
            }
        } else {
            double ps[2] = {0.0, 0.0};
            #pragma unroll
            for (int ot = 0; ot < 4; ++ot)
                #pragma unroll
                for (int v = 0; v < 4; ++v) {
                    const int cv = (var == 2) ? (4 * g + v) : (g + 4 * v);
                    const int o = oc + ot * 16 + cv;
                    const double bb = (double)b1[o];
                    const double ww = (double)w2[o];
                    #pragma unroll
                    for (int mt = 0; mt < 2; ++mt) {
                        const double u = acc[mt][ot][v] + bb;
                        ps[mt] += ww * (u / (1.0 + exp(-u)));
                    }
                }
            #pragma unroll
            for (int mt = 0; mt < 2; ++mt) {
                ps[mt] += __shfl_xor(ps[mt], 16, 64);
                ps[mt] += __shfl_xor(ps[mt], 32, 64);
            }
            if (g == 0) {
                spart[wave][a15]      = ps[0];
                spart[wave][16 + a15] = ps[1];
            }
        }
        __syncthreads();
        if (t < 32)
            s_out[m0 + t] = spart[0][t] + spart[1][t] + spart[2][t] + spart[3][t];
        return;
    }

    // -------- VALU fallback (r12 verified body): wave = 8 rows x all o --------
    {
        const int mv0 = m0 + wave * 8;
        const int o0 = lane * 4;
        const float* hr = hp + (size_t)mv0 * H_;
        const float* wp = W1T + o0;

        double acc[4][8];
        #pragma unroll
        for (int j = 0; j < 4; ++j)
            #pragma unroll
            for (int r = 0; r < 8; ++r) acc[j][r] = 0.0;

        float4 wA[4], wB[4];
        float hA[32], hB[32];     // 8 rows x 4 k

        #define VLOADW(dst, kcv)                                              \
            do {                                                              \
                _Pragma("unroll")                                             \
                for (int kk = 0; kk < 4; ++kk)                                \
                    dst[kk] = *reinterpret_cast<const float4*>(               \
                        wp + (size_t)((kcv) + kk) * H_);                      \
            } while (0)

        #define VLOADH(dst, kcv)                                              \
            do {                                                              \
                _Pragma("unroll")                                             \
                for (int r = 0; r < 8; ++r)                                   \
                    _Pragma("unroll")                                         \
                    for (int kk = 0; kk < 4; ++kk)                            \
                        dst[r * 4 + kk] = hr[r * H_ + (kcv) + kk];            \
            } while (0)

        #define VCOMPUTE(wv, hbuf)                                            \
            do {                                                              \
                _Pragma("unroll")                                             \
                for (int kk = 0; kk < 4; ++kk) {                              \
                    const double a0 = (double)wv[kk].x;                       \
                    const double a1 = (double)wv[kk].y;                       \
                    const double a2 = (double)wv[kk].z;                       \
                    const double a3 = (double)wv[kk].w;                       \
                    _Pragma("unroll")                                         \
                    for (int r = 0; r < 8; ++r) {                             \
                        const double hv = (double)hbuf[r * 4 + kk];           \
                        acc[0][r] = fma(a0, hv, acc[0][r]);                   \
                        acc[1][r] = fma(a1, hv, acc[1][r]);                   \
                        acc[2][r] = fma(a2, hv, acc[2][r]);                   \
                        acc[3][r] = fma(a3, hv, acc[3][r]);                   \
                    }                                                         \
                }                                                             \
            } while (0)

        VLOADW(wA, 0);
        VLOADH(hA, 0);
        for (int kc = 0; kc < H_; kc += 8) {
            VLOADW(wB, kc + 4);
            VLOADH(hB, kc + 4);
            VCOMPUTE(wA, hA);
            if (kc + 8 < H_) {
                VLOADW(wA, kc + 8);
                VLOADH(hA, kc + 8);
            }
            VCOMPUTE(wB, hB);
        }
        #undef VLOADW
        #undef VLOADH
        #undef VCOMPUTE

        const float4 b1v = *reinterpret_cast<const float4*>(b1 + o0);
        const float4 w2v = *reinterpret_cast<const float4*>(w2 + o0);
        double psum[8] = {0.0, 0.0, 0.0, 0.0, 0.0, 0.0, 0.0, 0.0};
        #define VEPI(j, bc, wc)                                               \
            do {                                                              \
                const double bb = (double)bc, ww = (double)wc;                \
                _Pragma("unroll")                                             \
                for (int r = 0; r < 8; ++r) {                                 \
                    const double u = acc[j][r] + bb;                          \
                    psum[r] += ww * (u / (1.0 + exp(-u)));                    \
                }                                                             \
            } while (0)
        VEPI(0, b1v.x, w2v.x);
        VEPI(1, b1v.y, w2v.y);
        VEPI(2, b1v.z, w2v.z);
        VEPI(3, b1v.w, w2v.w);
        #undef VEPI

        #pragma unroll
        for (int r = 0; r < 8; ++r) {
            double v = psum[r];
            v += __shfl_xor(v, 1, 64);
            v += __shfl_xor(v, 2, 64);
            v += __shfl_xor(v, 4, 64);
            v += __shfl_xor(v, 8, 64);
            v += __shfl_xor(v, 16, 64);
            v += __shfl_xor(v, 32, 64);
            if (lane == 0) s_out[mv0 + r] = v;
        }
    }
}

// Kernel B: out[b,i,j] = (int32)trunc( (s[b,i] - s[b,j]) + b2 )
__global__ __launch_bounds__(256)
void pair_kernel(const double* __restrict__ s, const float* __restrict__ b2p,
                 int* __restrict__ out) {
    const double b2 = (double)b2p[0];
    const unsigned total4 = (unsigned)(B_) * (unsigned)(N_) * (unsigned)(N_) / 4u;
    const unsigned stride = gridDim.x * blockDim.x;
    for (unsigned idx = blockIdx.x * blockDim.x + threadIdx.x; idx < total4;
         idx += stride) {
        const unsigned base = idx * 4u;                 // element index, %4==0
        const unsigned bi  = base >> 22;                // / (N*N), N*N = 2^22
        const unsigned rem = base & ((1u << 22) - 1u);
        const unsigned i   = rem >> 11;                 // / N
        const unsigned j   = rem & (N_ - 1u);
        const double si = s[bi * N_ + i];
        const double* sp = s + bi * N_ + j;             // 32B aligned (j%4==0)
        const double sj0 = sp[0], sj1 = sp[1], sj2 = sp[2], sj3 = sp[3];
        int4 o;
        o.x = (int)trunc((si - sj0) + b2);
        o.y = (int)trunc((si - sj1) + b2);
        o.z = (int)trunc((si - sj2) + b2);
        o.w = (int)trunc((si - sj3) + b2);
        *reinterpret_cast<int4*>(out + base) = o;
    }
}

extern "C" void kernel_launch(void* const* d_in, const int* in_sizes, int n_in,
                              void* d_out, int out_size, void* d_ws, size_t ws_size,
                              hipStream_t stream) {
    const float* hp = (const float*)d_in[0];
    // d_in[1] = node_mask (unused), d_in[2] = n_nodes (unused)
    const float* W1 = (const float*)d_in[3];
    const float* b1 = (const float*)d_in[4];
    const float* w2 = (const float*)d_in[5];
    const float* b2 = (const float*)d_in[6];

    float*  W1T = (float*)d_ws;                                   // 256 KB
    double* s   = (double*)((char*)d_ws + 256 * 1024);            // 128 KB
    int* out = (int*)d_out;

    transpose_w1<<<H_, H_, 0, stream>>>(W1, W1T);
    s_kernel<<<(B_ * N_) / 32, 256, 0, stream>>>(hp, W1T, b1, w2, s);
    pair_kernel<<<2048, 256, 0, stream>>>(s, b2, out);
}